// Round 7
// baseline (2042.823 us; speedup 1.0000x reference)
//
#include <hip/hip_runtime.h>
#include <stdint.h>

#define NSAMP 16
#define BATCH 128
#define SEQLEN 32
#define SDIM 8
#define ODIM 4
#define HID 800
#define MROWS (NSAMP * BATCH) /* 2048 */
#define KEEPP 0.8f

// packed-weight geometry (ushort units unless noted)
#define WPK_NBLK 77824            /* 155648 B per 16-col n-block */
#define WPK_G 12928               /* 25856 B per gate */
#define WPK_C 808                 /* 1616 B per col row (800 + 8 pad for bank stride) */
#define GRU_LDS_BYTES 155648      /* 152 x 1024B segments */

typedef __attribute__((ext_vector_type(8))) short short8v;
typedef __attribute__((ext_vector_type(4))) float float4v;

// ---------------- threefry2x32 (JAX partitionable mode, verified R1) ----------------
__host__ __device__ __forceinline__ void tf2x32(uint32_t k0, uint32_t k1,
                                                uint32_t x0, uint32_t x1,
                                                uint32_t& o0, uint32_t& o1) {
  uint32_t ks2 = k0 ^ k1 ^ 0x1BD11BDAu;
  x0 += k0; x1 += k1;
#define TFR(r) { x0 += x1; x1 = (x1 << (r)) | (x1 >> (32 - (r))); x1 ^= x0; }
  TFR(13) TFR(15) TFR(26) TFR(6)
  x0 += k1; x1 += ks2 + 1u;
  TFR(17) TFR(29) TFR(16) TFR(24)
  x0 += ks2; x1 += k0 + 2u;
  TFR(13) TFR(15) TFR(26) TFR(6)
  x0 += k0; x1 += k1 + 3u;
  TFR(17) TFR(29) TFR(16) TFR(24)
  x0 += k1; x1 += ks2 + 4u;
  TFR(13) TFR(15) TFR(26) TFR(6)
  x0 += ks2; x1 += k0 + 5u;
#undef TFR
  o0 = x0; o1 = x1;
}

__device__ __forceinline__ float bits_to_unit(uint32_t bits) {
  return __uint_as_float((bits >> 9) | 0x3F800000u) - 1.0f;
}

__device__ __forceinline__ float tf_uniform_part(uint32_t k0, uint32_t k1, uint32_t idx) {
  uint32_t b1, b2;
  tf2x32(k0, k1, 0u, idx, b1, b2);
  return bits_to_unit(b1 ^ b2);
}

__device__ __forceinline__ ushort f2bf(float f) {
  uint32_t u = __float_as_uint(f);
  uint32_t r = (u + 0x7FFFu + ((u >> 16) & 1u)) >> 16;
  return (ushort)r;
}

__device__ __forceinline__ float bf2f(ushort u) {
  return __uint_as_float((uint32_t)u << 16);
}

// ---------------- pack weights into per-n-block LDS-image layout (once) ----------------
// Wpk[nblk 0..49][g 0..5][c 0..15][k 0..807] bf16; k>=800 zero-pad (bank stride 1616B).
__global__ void pack_w_kernel(const float* __restrict__ W_ih, const float* __restrict__ W_hh,
                              ushort* __restrict__ Wpk) {
  const int blk = blockIdx.x;          // nblk*6 + g
  const int nblk = blk / 6, g = blk % 6;
  const float* W = (g < 3) ? W_ih : W_hh;
  const int grow = (g % 3) * HID;
  ushort* dst = Wpk + (size_t)nblk * WPK_NBLK + (size_t)g * WPK_G;
  for (int idx = threadIdx.x; idx < 16 * WPK_C; idx += 256) {
    int c = idx / WPK_C, k = idx - c * WPK_C;
    float v = (k < HID) ? W[(size_t)(grow + nblk * 16 + c) * HID + k] : 0.0f;
    dst[c * WPK_C + k] = f2bf(v);
  }
}

__global__ void transpose_wout_kernel(const float* __restrict__ W_out, float* __restrict__ WoutT) {
  int i = blockIdx.x * 256 + threadIdx.x;
  if (i < 32 * HID) {
    int o = i / HID, k = i - o * HID;
    WoutT[k * 32 + o] = W_out[i];
  }
}

// ---------------- a_ens = bf16( a * m1 / keep ) ----------------
__global__ void a_ens_kernel(const float* __restrict__ a, ushort* __restrict__ aeb,
                             uint32_t k0, uint32_t k1) {
  int base = (blockIdx.x * blockDim.x + threadIdx.x) * 4;
  if (base >= MROWS * HID) return;
  int row = base / HID;
  int b = row % BATCH;
  int col = base - row * HID;
  float4 av = *reinterpret_cast<const float4*>(a + b * HID + col);
  ushort4 ov;
#pragma unroll
  for (int q = 0; q < 4; ++q) {
    float u = tf_uniform_part(k0, k1, (uint32_t)(base + q));
    float f = (&av.x)[q] * ((u < KEEPP) ? 1.25f : 0.0f);
    (&ov.x)[q] = f2bf(f);
  }
  *reinterpret_cast<ushort4*>(aeb + base) = ov;
}

// ---------------- MFMA GRU: whole B panel in LDS, barrier-free K-loop -----------------
// Grid 200 x 512. Block = (mblk 0..3 [TM=512], nblk 0..49 [TN=16], all 6 gates).
// XCD map: bid&7 = mblk*2 + (nblk&1)  ->  per-XCD A slice (1.64MB) is L2-resident.
// Stage: 152 linear global_load_lds(16B) segments of the packed B image -> 1 barrier.
// K-loop (25 tiles): 8 A-loads (direct global->reg, 1 tile ahead) + 6 ds_read_b128
// + 24 MFMA per wave; no barriers, no LDS writes; compiler schedules waits.
__global__ __launch_bounds__(512, 2) void gru_mfma_kernel(
    const ushort* __restrict__ aeb, const ushort* __restrict__ hb,
    const ushort* __restrict__ Wpk,
    const float* __restrict__ h_old,
    const float* __restrict__ b_ih, const float* __restrict__ b_hh,
    float* __restrict__ h_new, ushort* __restrict__ h_new_b) {
  extern __shared__ __align__(16) char lds[];

  const int tid = threadIdx.x;
  const int w = tid >> 6;          // 0..7
  const int lane = tid & 63;
  const int l15 = lane & 15;
  const int kg = lane >> 4;        // 0..3

  const int bid = blockIdx.x;      // 0..199
  const int nhalf = bid >> 3;      // 0..24
  const int r3 = bid & 7;
  const int mblk = r3 >> 1;        // 0..3
  const int nblk = nhalf * 2 + (r3 & 1);  // 0..49
  const int m0 = mblk * 512;
  const int n0 = nblk * 16;

  // ---- stage B panel: wave w copies segments [w*19, w*19+19)
  {
    const ushort* wsrc = Wpk + (size_t)nblk * WPK_NBLK + (size_t)lane * 8;
    for (int s = w * 19; s < w * 19 + 19; ++s) {
      __builtin_amdgcn_global_load_lds(
          (const __attribute__((address_space(1))) void*)(wsrc + (size_t)s * 512),
          (__attribute__((address_space(3))) void*)(lds + s * 1024), 16, 0, 0);
    }
  }

  float4v acc[6][4];
#pragma unroll
  for (int g = 0; g < 6; ++g)
#pragma unroll
    for (int mf = 0; mf < 4; ++mf)
      acc[g][mf] = (float4v)(0.0f);

  // ---- A fragment pointers (MFMA A layout: row = l15, k-chunk = kg)
  const ushort* ap[2][4];
#pragma unroll
  for (int mf = 0; mf < 4; ++mf) {
    const int row = m0 + w * 64 + mf * 16 + l15;
    ap[0][mf] = aeb + (size_t)row * HID + kg * 8;
    ap[1][mf] = hb + (size_t)row * HID + kg * 8;
  }
  short8v ar0[2][4], ar1[2][4];

#define LOADA(SET) do {                                                          \
    _Pragma("unroll")                                                            \
    for (int s2 = 0; s2 < 2; ++s2)                                               \
      _Pragma("unroll")                                                          \
      for (int mf = 0; mf < 4; ++mf) {                                           \
        SET[s2][mf] = *reinterpret_cast<const short8v*>(ap[s2][mf]);             \
        ap[s2][mf] += 32;                                                        \
      }                                                                          \
  } while (0)

#define COMP(T, SET) do {                                                        \
    short8v bfr[6];                                                              \
    _Pragma("unroll")                                                            \
    for (int g = 0; g < 6; ++g)                                                  \
      bfr[g] = *reinterpret_cast<const short8v*>(                                \
          lds + g * 25856 + l15 * 1616 + (T) * 64 + kg * 16);                    \
    __builtin_amdgcn_s_setprio(1);                                               \
    _Pragma("unroll")                                                            \
    for (int g = 0; g < 6; ++g) {                                                \
      const int src = (g < 3) ? 0 : 1;                                           \
      _Pragma("unroll")                                                          \
      for (int mf = 0; mf < 4; ++mf)                                             \
        acc[g][mf] = __builtin_amdgcn_mfma_f32_16x16x32_bf16(                    \
            SET[src][mf], bfr[g], acc[g][mf], 0, 0, 0);                          \
    }                                                                            \
    __builtin_amdgcn_s_setprio(0);                                               \
  } while (0)

  LOADA(ar0);                       // tile 0 A-frags (overlaps with B staging)
  asm volatile("s_waitcnt vmcnt(0)" ::: "memory");
  __syncthreads();                  // B panel resident; no further barriers

#pragma unroll 1
  for (int t = 0; t < 24; t += 2) {
    LOADA(ar1);                     // tile t+1
    COMP(t, ar0);
    LOADA(ar0);                     // tile t+2 (t=22 -> tile 24, last)
    COMP(t + 1, ar1);
  }
  COMP(24, ar0);

  // ---- epilogue: gates + state; C/D: col=l15, row=(lane>>4)*4+reg
  const int rowq = (lane >> 4) * 4;
  const int col = n0 + l15;
  const float bir = b_ih[col], biz = b_ih[col + HID], bin = b_ih[col + 2 * HID];
  const float bhr = b_hh[col], bhz = b_hh[col + HID], bhn = b_hh[col + 2 * HID];
#pragma unroll
  for (int mf = 0; mf < 4; ++mf) {
#pragma unroll
    for (int reg = 0; reg < 4; ++reg) {
      const int m = m0 + w * 64 + mf * 16 + rowq + reg;
      float gir = acc[0][mf][reg] + bir;
      float giz = acc[1][mf][reg] + biz;
      float gin = acc[2][mf][reg] + bin;
      float ghr = acc[3][mf][reg] + bhr;
      float ghz = acc[4][mf][reg] + bhz;
      float ghn = acc[5][mf][reg] + bhn;
      float r = 1.0f / (1.0f + expf(-(gir + ghr)));
      float z = 1.0f / (1.0f + expf(-(giz + ghz)));
      float nval = tanhf(gin + r * ghn);
      float hv = h_old[(size_t)m * HID + col];
      float res = (1.0f - z) * nval + z * hv;
      h_new[(size_t)m * HID + col] = res;
      h_new_b[(size_t)m * HID + col] = f2bf(res);
    }
  }
#undef LOADA
#undef COMP
}

// ---------------- K_vec = h_new(bf16) @ W_out^T + b_out, dropout m2, ens ----------------
__global__ void kvec_ens_kernel(const ushort* __restrict__ hnb,
                                const float* __restrict__ WoutT,  // [HID][32]
                                const float* __restrict__ b_out,
                                const float* __restrict__ x_pred, // [B][8]
                                const float* __restrict__ innov,  // [B][4]
                                float* __restrict__ ens,          // [NS][B][8]
                                uint32_t k0, uint32_t k1) {
  const int jb = blockIdx.x;
  const int b = jb & (BATCH - 1);
  const int tid = threadIdx.x;
  const int o = tid & 31;
  const int kk = tid >> 5;

  const ushort* hrow = hnb + (size_t)jb * HID + kk * 100;
  const float* wc = WoutT + kk * 100 * 32 + o;
  float partial = 0.0f;
  for (int k = 0; k < 100; ++k)
    partial = fmaf(bf2f(hrow[k]), wc[k * 32], partial);

  __shared__ float red[8][32];
  __shared__ float Kv[32];
  red[kk][o] = partial;
  __syncthreads();
  if (tid < 32) {
    float s = 0.0f;
#pragma unroll
    for (int q = 0; q < 8; ++q) s += red[q][tid];
    s += b_out[tid];
    float u = tf_uniform_part(k0, k1, (uint32_t)(jb * 32 + tid));
    Kv[tid] = (u < KEEPP) ? s * 1.25f : 0.0f;
  }
  __syncthreads();
  if (tid < SDIM) {
    float s = x_pred[b * SDIM + tid];
#pragma unroll
    for (int oo = 0; oo < ODIM; ++oo)
      s = fmaf(Kv[tid * ODIM + oo], innov[b * ODIM + oo], s);
    ens[jb * SDIM + tid] = s;
  }
}

// ---------------- ensemble stats + outputs + prep of next step (128 blocks) ------------
__global__ void reduce_prep_kernel(const float* __restrict__ ens,
                                   float* __restrict__ x_pred,
                                   float* __restrict__ innov,
                                   const float* __restrict__ y_seq,
                                   const float* __restrict__ W1,
                                   const float* __restrict__ b1,
                                   float* __restrict__ a,
                                   float* __restrict__ out_xs, float* __restrict__ out_Ps,
                                   int t) {
  const int b = blockIdx.x;
  const int tid = threadIdx.x;
  __shared__ float e[NSAMP][SDIM];
  __shared__ float xf[SDIM];
  __shared__ float dxs[SDIM];
  __shared__ float xpn[SDIM];
  __shared__ float inv[ODIM];
  __shared__ float nin[SDIM + ODIM];

  if (t >= 0) {
    if (tid < NSAMP * SDIM) {
      int j = tid >> 3, s = tid & 7;
      e[j][s] = ens[(j * BATCH + b) * SDIM + s];
    }
    __syncthreads();
    if (tid < SDIM) {
      float s = 0.0f;
#pragma unroll
      for (int j = 0; j < NSAMP; ++j) s += e[j][tid];
      s *= (1.0f / NSAMP);
      xf[tid] = s;
      out_xs[(b * SEQLEN + t) * SDIM + tid] = s;
      dxs[tid] = s - x_pred[b * SDIM + tid];
    }
    __syncthreads();
    if (tid < SDIM * SDIM) {
      int s = tid >> 3, u = tid & 7;
      float accv = 0.0f;
#pragma unroll
      for (int j = 0; j < NSAMP; ++j)
        accv += (e[j][s] - xf[s]) * (e[j][u] - xf[u]);
      out_Ps[((b * SEQLEN + t) * SDIM + s) * SDIM + u] = accv * (1.0f / NSAMP);
    }
  } else {
    if (tid < SDIM) { xf[tid] = 0.0f; dxs[tid] = 0.0f; }
  }
  if (t == SEQLEN - 1) return;
  __syncthreads();
  if (tid < SDIM) {
    float x = xf[tid];
    float xp = 0.9f * x + 0.1f * sinf(x);
    xpn[tid] = xp;
    x_pred[b * SDIM + tid] = xp;
  }
  __syncthreads();
  if (tid < ODIM) {
    float yh = tanhf(xpn[tid]);
    float iv = y_seq[(b * SEQLEN + (t + 1)) * ODIM + tid] - yh;
    inv[tid] = iv;
    innov[b * ODIM + tid] = iv;
  }
  __syncthreads();
  if (tid == 0) {
    float nd = 0.0f;
    for (int s = 0; s < SDIM; ++s) nd += dxs[s] * dxs[s];
    nd = fmaxf(sqrtf(nd), 1e-12f);
    for (int s = 0; s < SDIM; ++s) nin[s] = dxs[s] / nd;
    float ni = 0.0f;
    for (int o2 = 0; o2 < ODIM; ++o2) ni += inv[o2] * inv[o2];
    ni = fmaxf(sqrtf(ni), 1e-12f);
    for (int o2 = 0; o2 < ODIM; ++o2) nin[SDIM + o2] = inv[o2] / ni;
  }
  __syncthreads();
  for (int i = tid; i < HID; i += blockDim.x) {
    float s = b1[i];
#pragma unroll
    for (int c = 0; c < 12; ++c) s = fmaf(nin[c], W1[i * 12 + c], s);
    a[b * HID + i] = fmaxf(s, 0.0f);
  }
}

extern "C" void kernel_launch(void* const* d_in, const int* in_sizes, int n_in,
                              void* d_out, int out_size, void* d_ws, size_t ws_size,
                              hipStream_t stream) {
  (void)in_sizes; (void)n_in; (void)out_size; (void)ws_size;
  const float* y_seq = (const float*)d_in[0];
  const float* W1 = (const float*)d_in[1];
  const float* b1 = (const float*)d_in[2];
  const float* W_ih = (const float*)d_in[3];
  const float* W_hh = (const float*)d_in[4];
  const float* b_ih = (const float*)d_in[5];
  const float* b_hh = (const float*)d_in[6];
  const float* W_out = (const float*)d_in[7];
  const float* b_out = (const float*)d_in[8];

  char* ws = (char*)d_ws;
  size_t off = 0;
  float* h_a = (float*)(ws + off);    off += (size_t)MROWS * HID * 4;
  float* h_b = (float*)(ws + off);    off += (size_t)MROWS * HID * 4;
  ushort* hb_a = (ushort*)(ws + off); off += (size_t)MROWS * HID * 2;
  ushort* hb_b = (ushort*)(ws + off); off += (size_t)MROWS * HID * 2;
  ushort* aeb = (ushort*)(ws + off);  off += (size_t)MROWS * HID * 2;
  ushort* Wpk = (ushort*)(ws + off);  off += (size_t)50 * WPK_NBLK * 2;
  float* a_buf = (float*)(ws + off);  off += (size_t)BATCH * HID * 4;
  float* WoutT = (float*)(ws + off);  off += (size_t)HID * 32 * 4;
  float* x_pred = (float*)(ws + off); off += (size_t)BATCH * SDIM * 4;
  float* innov = (float*)(ws + off);  off += (size_t)BATCH * ODIM * 4;
  float* ens = (float*)(ws + off);    off += (size_t)NSAMP * BATCH * SDIM * 4;

  float* out_xs = (float*)d_out;
  float* out_Ps = out_xs + (size_t)BATCH * SEQLEN * SDIM;

  // allow >64KB dynamic LDS for the GRU kernel (idempotent; no stream interaction)
  (void)hipFuncSetAttribute(reinterpret_cast<const void*>(&gru_mfma_kernel),
                            hipFuncAttributeMaxDynamicSharedMemorySize, GRU_LDS_BYTES);

  hipMemsetAsync(h_a, 0, (size_t)MROWS * HID * 4, stream);
  hipMemsetAsync(hb_a, 0, (size_t)MROWS * HID * 2, stream);
  pack_w_kernel<<<300, 256, 0, stream>>>(W_ih, W_hh, Wpk);
  transpose_wout_kernel<<<100, 256, 0, stream>>>(W_out, WoutT);
  reduce_prep_kernel<<<BATCH, 256, 0, stream>>>(ens, x_pred, innov, y_seq, W1, b1,
                                                a_buf, out_xs, out_Ps, -1);

  float* hc = h_a;  float* hn = h_b;
  ushort* hcb = hb_a; ushort* hnb = hb_b;
  for (int t = 0; t < SEQLEN; ++t) {
    uint32_t kt0, kt1, k1a, k1b, k2a, k2b;
    tf2x32(0u, 42u, 0u, (uint32_t)t, kt0, kt1);   // fold_in(key(42), t)
    tf2x32(kt0, kt1, 0u, 0u, k1a, k1b);           // dropout1 key
    tf2x32(kt0, kt1, 0u, 1u, k2a, k2b);           // dropout2 key

    a_ens_kernel<<<1600, 256, 0, stream>>>(a_buf, aeb, k1a, k1b);
    gru_mfma_kernel<<<200, 512, GRU_LDS_BYTES, stream>>>(aeb, hcb, Wpk, hc,
                                                         b_ih, b_hh, hn, hnb);
    kvec_ens_kernel<<<MROWS, 256, 0, stream>>>(hnb, WoutT, b_out, x_pred, innov, ens, k2a, k2b);
    reduce_prep_kernel<<<BATCH, 256, 0, stream>>>(ens, x_pred, innov, y_seq, W1, b1,
                                                  a_buf, out_xs, out_Ps, t);
    float* tmp = hc; hc = hn; hn = tmp;
    ushort* tmpb = hcb; hcb = hnb; hnb = tmpb;
  }
}

// Round 8
// 1734.650 us; speedup vs baseline: 1.1777x; 1.1777x over previous
//
#include <hip/hip_runtime.h>
#include <stdint.h>

#define NSAMP 16
#define BATCH 128
#define SEQLEN 32
#define SDIM 8
#define ODIM 4
#define HID 800
#define MROWS (NSAMP * BATCH) /* 2048 */
#define KEEPP 0.8f

// packed-weight geometry (ushort units unless noted)
#define WPK_NBLK 77824            /* 155648 B per 16-col n-block */
#define WPK_G 12928               /* 25856 B per gate */
#define WPK_C 808                 /* 1616 B per col row (800 + 8 pad) */
#define GRU_LDS_BYTES 155648      /* 152 x 1024B segments */

typedef __attribute__((ext_vector_type(8))) short short8v;
typedef __attribute__((ext_vector_type(4))) float float4v;

// ---------------- threefry2x32 (JAX partitionable mode, verified R1) ----------------
__host__ __device__ __forceinline__ void tf2x32(uint32_t k0, uint32_t k1,
                                                uint32_t x0, uint32_t x1,
                                                uint32_t& o0, uint32_t& o1) {
  uint32_t ks2 = k0 ^ k1 ^ 0x1BD11BDAu;
  x0 += k0; x1 += k1;
#define TFR(r) { x0 += x1; x1 = (x1 << (r)) | (x1 >> (32 - (r))); x1 ^= x0; }
  TFR(13) TFR(15) TFR(26) TFR(6)
  x0 += k1; x1 += ks2 + 1u;
  TFR(17) TFR(29) TFR(16) TFR(24)
  x0 += ks2; x1 += k0 + 2u;
  TFR(13) TFR(15) TFR(26) TFR(6)
  x0 += k0; x1 += k1 + 3u;
  TFR(17) TFR(29) TFR(16) TFR(24)
  x0 += k1; x1 += ks2 + 4u;
  TFR(13) TFR(15) TFR(26) TFR(6)
  x0 += ks2; x1 += k0 + 5u;
#undef TFR
  o0 = x0; o1 = x1;
}

__device__ __forceinline__ float bits_to_unit(uint32_t bits) {
  return __uint_as_float((bits >> 9) | 0x3F800000u) - 1.0f;
}

__device__ __forceinline__ float tf_uniform_part(uint32_t k0, uint32_t k1, uint32_t idx) {
  uint32_t b1, b2;
  tf2x32(k0, k1, 0u, idx, b1, b2);
  return bits_to_unit(b1 ^ b2);
}

__device__ __forceinline__ ushort f2bf(float f) {
  uint32_t u = __float_as_uint(f);
  uint32_t r = (u + 0x7FFFu + ((u >> 16) & 1u)) >> 16;
  return (ushort)r;
}

// ---------------- pack weights into per-n-block LDS-image layout (once) ----------------
__global__ void pack_w_kernel(const float* __restrict__ W_ih, const float* __restrict__ W_hh,
                              ushort* __restrict__ Wpk) {
  const int blk = blockIdx.x;          // nblk*6 + g
  const int nblk = blk / 6, g = blk % 6;
  const float* W = (g < 3) ? W_ih : W_hh;
  const int grow = (g % 3) * HID;
  ushort* dst = Wpk + (size_t)nblk * WPK_NBLK + (size_t)g * WPK_G;
  for (int idx = threadIdx.x; idx < 16 * WPK_C; idx += 256) {
    int c = idx / WPK_C, k = idx - c * WPK_C;
    float v = (k < HID) ? W[(size_t)(grow + nblk * 16 + c) * HID + k] : 0.0f;
    dst[c * WPK_C + k] = f2bf(v);
  }
}

__global__ void transpose_wout_kernel(const float* __restrict__ W_out, float* __restrict__ WoutT) {
  int i = blockIdx.x * 256 + threadIdx.x;
  if (i < 32 * HID) {
    int o = i / HID, k = i - o * HID;
    WoutT[k * 32 + o] = W_out[i];
  }
}

// ---------------- a_ens -> fragment-major AF --------------------------------------------
// AF[(mt*25+kt)*64 + lane][8]: lane holds A[row=mt*16+(lane&15)][k=kt*32+(lane>>4)*8 ..+8]
// One wave per (mt,kt) fragment tile; 3200 waves = 800 blocks x 4 waves.
__global__ void a_ens_kernel(const float* __restrict__ a_buf, ushort* __restrict__ AF,
                             uint32_t k0, uint32_t k1) {
  const int gw = blockIdx.x * 4 + (threadIdx.x >> 6);   // 0..3199 = mt*25+kt
  const int lane = threadIdx.x & 63;
  const int mt = gw / 25, kt = gw - mt * 25;
  const int row = mt * 16 + (lane & 15);
  const int b = row & (BATCH - 1);
  const int k = kt * 32 + (lane >> 4) * 8;
  const float* src = a_buf + (size_t)b * HID + k;
  float4 v0 = *reinterpret_cast<const float4*>(src);
  float4 v1 = *reinterpret_cast<const float4*>(src + 4);
  const uint32_t base = (uint32_t)(row * HID + k);
  ushort o[8];
#pragma unroll
  for (int q = 0; q < 4; ++q) {
    float u = tf_uniform_part(k0, k1, base + q);
    o[q] = f2bf((&v0.x)[q] * ((u < KEEPP) ? 1.25f : 0.0f));
  }
#pragma unroll
  for (int q = 0; q < 4; ++q) {
    float u = tf_uniform_part(k0, k1, base + 4 + q);
    o[4 + q] = f2bf((&v1.x)[q] * ((u < KEEPP) ? 1.25f : 0.0f));
  }
  *reinterpret_cast<short8v*>(AF + ((size_t)gw * 64 + lane) * 8) =
      *reinterpret_cast<const short8v*>(o);
}

// ---------------- MFMA GRU: B panel in LDS, frag-major A, 2-deep prefetch --------------
// Grid 200 x 512. Block = (mblk [TM=512], nblk [TN=16], all 6 gates).
// A-loads: 8 per wave per tile, each a CONTIGUOUS 1KB (lane*16B) from AF/HF.
// HF layout per 16x16 tile (512B): off = ((col>>3)&1)*256 + (row&15)*16 + (col&7)*2,
// so a k-tile read (32 cols = 2 adjacent tiles) is exactly base + lane*16B.
__global__ __launch_bounds__(512, 2) void gru_mfma_kernel(
    const ushort* __restrict__ AF, const ushort* __restrict__ HF,
    const ushort* __restrict__ Wpk,
    const float* __restrict__ h_old,
    const float* __restrict__ b_ih, const float* __restrict__ b_hh,
    float* __restrict__ h_new, ushort* __restrict__ hf_out) {
  extern __shared__ __align__(16) char lds[];

  const int tid = threadIdx.x;
  const int w = tid >> 6;          // 0..7
  const int lane = tid & 63;
  const int l15 = lane & 15;
  const int kg = lane >> 4;        // 0..3

  const int bid = blockIdx.x;      // 0..199
  const int nhalf = bid >> 3;      // 0..24
  const int r3 = bid & 7;
  const int mblk = r3 >> 1;        // 0..3
  const int nblk = nhalf * 2 + (r3 & 1);  // 0..49
  const int m0 = mblk * 512;
  const int n0 = nblk * 16;
  const int mtb = mblk * 32;       // base mt of this block

  // ---- stage B panel: wave w copies segments [w*19, w*19+19)
  {
    const ushort* wsrc = Wpk + (size_t)nblk * WPK_NBLK + (size_t)lane * 8;
    for (int s = w * 19; s < w * 19 + 19; ++s) {
      __builtin_amdgcn_global_load_lds(
          (const __attribute__((address_space(1))) void*)(wsrc + (size_t)s * 512),
          (__attribute__((address_space(3))) void*)(lds + s * 1024), 16, 0, 0);
    }
  }

  float4v acc[6][4];
#pragma unroll
  for (int g = 0; g < 6; ++g)
#pragma unroll
    for (int mf = 0; mf < 4; ++mf)
      acc[g][mf] = (float4v)(0.0f);

  // ---- A fragment pointers: both AF and HF have per-mt stride 12800 ushorts,
  // per-k-tile stride 512 ushorts, per-lane offset lane*8.
  const ushort* ap[2][4];
#pragma unroll
  for (int mf = 0; mf < 4; ++mf) {
    const size_t mt = (size_t)(mtb + w * 4 + mf);
    ap[0][mf] = AF + mt * 12800 + (size_t)lane * 8;
    ap[1][mf] = HF + mt * 12800 + (size_t)lane * 8;
  }
  short8v s0[2][4], s1[2][4], s2[2][4];

#define LOADA(SET) do {                                                          \
    _Pragma("unroll")                                                            \
    for (int sx = 0; sx < 2; ++sx)                                               \
      _Pragma("unroll")                                                          \
      for (int mf = 0; mf < 4; ++mf) {                                           \
        SET[sx][mf] = *reinterpret_cast<const short8v*>(ap[sx][mf]);             \
        ap[sx][mf] += 512;                                                       \
      }                                                                          \
  } while (0)

#define COMP(T, SET) do {                                                        \
    short8v bfr[6];                                                              \
    _Pragma("unroll")                                                            \
    for (int g = 0; g < 6; ++g)                                                  \
      bfr[g] = *reinterpret_cast<const short8v*>(                                \
          lds + g * 25856 + l15 * 1616 + (T) * 64 + kg * 16);                    \
    __builtin_amdgcn_s_setprio(1);                                               \
    _Pragma("unroll")                                                            \
    for (int g = 0; g < 6; ++g) {                                                \
      const int src = (g < 3) ? 0 : 1;                                           \
      _Pragma("unroll")                                                          \
      for (int mf = 0; mf < 4; ++mf)                                             \
        acc[g][mf] = __builtin_amdgcn_mfma_f32_16x16x32_bf16(                    \
            SET[src][mf], bfr[g], acc[g][mf], 0, 0, 0);                          \
    }                                                                            \
    __builtin_amdgcn_s_setprio(0);                                               \
  } while (0)

  LOADA(s0);                        // tile 0
  LOADA(s1);                        // tile 1
  asm volatile("s_waitcnt vmcnt(16)" ::: "memory");  // B panel + t0 A done
  __syncthreads();                  // B panel resident; no further barriers

#pragma unroll 1
  for (int t = 0; t < 21; t += 3) {
    LOADA(s2);                                            // tile t+2
    asm volatile("s_waitcnt vmcnt(16)" ::: "memory");     // tile t A done
    COMP(t, s0);
    LOADA(s0);                                            // tile t+3
    asm volatile("s_waitcnt vmcnt(16)" ::: "memory");     // tile t+1 done
    COMP(t + 1, s1);
    LOADA(s1);                                            // tile t+4
    asm volatile("s_waitcnt vmcnt(16)" ::: "memory");     // tile t+2 done
    COMP(t + 2, s2);
  }
  // tail: tiles 21..24
  LOADA(s2);                                              // tile 23
  asm volatile("s_waitcnt vmcnt(16)" ::: "memory");
  COMP(21, s0);
  LOADA(s0);                                              // tile 24
  asm volatile("s_waitcnt vmcnt(16)" ::: "memory");
  COMP(22, s1);
  asm volatile("s_waitcnt vmcnt(8)" ::: "memory");
  COMP(23, s2);
  asm volatile("s_waitcnt vmcnt(0)" ::: "memory");
  COMP(24, s0);

  // ---- epilogue: gates + state; C/D: col=l15, row=(lane>>4)*4+reg
  const int rowq = (lane >> 4) * 4;
  const int col = n0 + l15;
  const float bir = b_ih[col], biz = b_ih[col + HID], bin = b_ih[col + 2 * HID];
  const float bhr = b_hh[col], bhz = b_hh[col + HID], bhn = b_hh[col + 2 * HID];
  const int khalf = (l15 >> 3) & 1;
  const int kq = l15 & 7;
#pragma unroll
  for (int mf = 0; mf < 4; ++mf) {
    const size_t mt = (size_t)(mtb + w * 4 + mf);
    ushort* hfw = hf_out + mt * 12800 + (size_t)nblk * 256 + khalf * 128 + kq;
#pragma unroll
    for (int reg = 0; reg < 4; ++reg) {
      const int m = m0 + w * 64 + mf * 16 + rowq + reg;
      float gir = acc[0][mf][reg] + bir;
      float giz = acc[1][mf][reg] + biz;
      float gin = acc[2][mf][reg] + bin;
      float ghr = acc[3][mf][reg] + bhr;
      float ghz = acc[4][mf][reg] + bhz;
      float ghn = acc[5][mf][reg] + bhn;
      float r = 1.0f / (1.0f + expf(-(gir + ghr)));
      float z = 1.0f / (1.0f + expf(-(giz + ghz)));
      float nval = tanhf(gin + r * ghn);
      float hv = h_old[(size_t)m * HID + col];
      float res = (1.0f - z) * nval + z * hv;
      h_new[(size_t)m * HID + col] = res;
      hfw[(rowq + reg) * 8] = f2bf(res);
    }
  }
#undef LOADA
#undef COMP
}

// ---------------- K_vec = h_new @ W_out^T + b_out, dropout m2, ens (2048 blocks) -------
__global__ void kvec_ens_kernel(const float* __restrict__ h_new,
                                const float* __restrict__ WoutT,  // [HID][32]
                                const float* __restrict__ b_out,
                                const float* __restrict__ x_pred, // [B][8]
                                const float* __restrict__ innov,  // [B][4]
                                float* __restrict__ ens,          // [NS][B][8]
                                uint32_t k0, uint32_t k1) {
  const int jb = blockIdx.x;
  const int b = jb & (BATCH - 1);
  const int tid = threadIdx.x;
  const int o = tid & 31;
  const int kk = tid >> 5;

  const float* hrow = h_new + (size_t)jb * HID;
  float partial = 0.0f;
  for (int k = kk * 100; k < kk * 100 + 100; ++k)
    partial = fmaf(hrow[k], WoutT[k * 32 + o], partial);

  __shared__ float red[8][32];
  __shared__ float Kv[32];
  red[kk][o] = partial;
  __syncthreads();
  if (tid < 32) {
    float s = 0.0f;
#pragma unroll
    for (int q = 0; q < 8; ++q) s += red[q][tid];
    s += b_out[tid];
    float u = tf_uniform_part(k0, k1, (uint32_t)(jb * 32 + tid));
    Kv[tid] = (u < KEEPP) ? s * 1.25f : 0.0f;
  }
  __syncthreads();
  if (tid < SDIM) {
    float s = x_pred[b * SDIM + tid];
#pragma unroll
    for (int oo = 0; oo < ODIM; ++oo)
      s = fmaf(Kv[tid * ODIM + oo], innov[b * ODIM + oo], s);
    ens[jb * SDIM + tid] = s;
  }
}

// ---------------- ensemble stats + outputs + prep of next step (128 blocks) ------------
__global__ void reduce_prep_kernel(const float* __restrict__ ens,
                                   float* __restrict__ x_pred,
                                   float* __restrict__ innov,
                                   const float* __restrict__ y_seq,
                                   const float* __restrict__ W1,
                                   const float* __restrict__ b1,
                                   float* __restrict__ a,
                                   float* __restrict__ out_xs, float* __restrict__ out_Ps,
                                   int t) {
  const int b = blockIdx.x;
  const int tid = threadIdx.x;
  __shared__ float e[NSAMP][SDIM];
  __shared__ float xf[SDIM];
  __shared__ float dxs[SDIM];
  __shared__ float xpn[SDIM];
  __shared__ float inv[ODIM];
  __shared__ float nin[SDIM + ODIM];

  if (t >= 0) {
    if (tid < NSAMP * SDIM) {
      int j = tid >> 3, s = tid & 7;
      e[j][s] = ens[(j * BATCH + b) * SDIM + s];
    }
    __syncthreads();
    if (tid < SDIM) {
      float s = 0.0f;
#pragma unroll
      for (int j = 0; j < NSAMP; ++j) s += e[j][tid];
      s *= (1.0f / NSAMP);
      xf[tid] = s;
      out_xs[(b * SEQLEN + t) * SDIM + tid] = s;
      dxs[tid] = s - x_pred[b * SDIM + tid];
    }
    __syncthreads();
    if (tid < SDIM * SDIM) {
      int s = tid >> 3, u = tid & 7;
      float accv = 0.0f;
#pragma unroll
      for (int j = 0; j < NSAMP; ++j)
        accv += (e[j][s] - xf[s]) * (e[j][u] - xf[u]);
      out_Ps[((b * SEQLEN + t) * SDIM + s) * SDIM + u] = accv * (1.0f / NSAMP);
    }
  } else {
    if (tid < SDIM) { xf[tid] = 0.0f; dxs[tid] = 0.0f; }
  }
  if (t == SEQLEN - 1) return;
  __syncthreads();
  if (tid < SDIM) {
    float x = xf[tid];
    float xp = 0.9f * x + 0.1f * sinf(x);
    xpn[tid] = xp;
    x_pred[b * SDIM + tid] = xp;
  }
  __syncthreads();
  if (tid < ODIM) {
    float yh = tanhf(xpn[tid]);
    float iv = y_seq[(b * SEQLEN + (t + 1)) * ODIM + tid] - yh;
    inv[tid] = iv;
    innov[b * ODIM + tid] = iv;
  }
  __syncthreads();
  if (tid == 0) {
    float nd = 0.0f;
    for (int s = 0; s < SDIM; ++s) nd += dxs[s] * dxs[s];
    nd = fmaxf(sqrtf(nd), 1e-12f);
    for (int s = 0; s < SDIM; ++s) nin[s] = dxs[s] / nd;
    float ni = 0.0f;
    for (int o2 = 0; o2 < ODIM; ++o2) ni += inv[o2] * inv[o2];
    ni = fmaxf(sqrtf(ni), 1e-12f);
    for (int o2 = 0; o2 < ODIM; ++o2) nin[SDIM + o2] = inv[o2] / ni;
  }
  __syncthreads();
  for (int i = tid; i < HID; i += blockDim.x) {
    float s = b1[i];
#pragma unroll
    for (int c = 0; c < 12; ++c) s = fmaf(nin[c], W1[i * 12 + c], s);
    a[b * HID + i] = fmaxf(s, 0.0f);
  }
}

extern "C" void kernel_launch(void* const* d_in, const int* in_sizes, int n_in,
                              void* d_out, int out_size, void* d_ws, size_t ws_size,
                              hipStream_t stream) {
  (void)in_sizes; (void)n_in; (void)out_size; (void)ws_size;
  const float* y_seq = (const float*)d_in[0];
  const float* W1 = (const float*)d_in[1];
  const float* b1 = (const float*)d_in[2];
  const float* W_ih = (const float*)d_in[3];
  const float* W_hh = (const float*)d_in[4];
  const float* b_ih = (const float*)d_in[5];
  const float* b_hh = (const float*)d_in[6];
  const float* W_out = (const float*)d_in[7];
  const float* b_out = (const float*)d_in[8];

  char* ws = (char*)d_ws;
  size_t off = 0;
  float* h_a = (float*)(ws + off);    off += (size_t)MROWS * HID * 4;
  float* h_b = (float*)(ws + off);    off += (size_t)MROWS * HID * 4;
  ushort* hf_a = (ushort*)(ws + off); off += (size_t)MROWS * HID * 2;
  ushort* hf_b = (ushort*)(ws + off); off += (size_t)MROWS * HID * 2;
  ushort* AF = (ushort*)(ws + off);   off += (size_t)MROWS * HID * 2;
  ushort* Wpk = (ushort*)(ws + off);  off += (size_t)50 * WPK_NBLK * 2;
  float* a_buf = (float*)(ws + off);  off += (size_t)BATCH * HID * 4;
  float* WoutT = (float*)(ws + off);  off += (size_t)HID * 32 * 4;
  float* x_pred = (float*)(ws + off); off += (size_t)BATCH * SDIM * 4;
  float* innov = (float*)(ws + off);  off += (size_t)BATCH * ODIM * 4;
  float* ens = (float*)(ws + off);    off += (size_t)NSAMP * BATCH * SDIM * 4;

  float* out_xs = (float*)d_out;
  float* out_Ps = out_xs + (size_t)BATCH * SEQLEN * SDIM;

  (void)hipFuncSetAttribute(reinterpret_cast<const void*>(&gru_mfma_kernel),
                            hipFuncAttributeMaxDynamicSharedMemorySize, GRU_LDS_BYTES);

  hipMemsetAsync(h_a, 0, (size_t)MROWS * HID * 4, stream);
  hipMemsetAsync(hf_a, 0, (size_t)MROWS * HID * 2, stream);
  pack_w_kernel<<<300, 256, 0, stream>>>(W_ih, W_hh, Wpk);
  transpose_wout_kernel<<<100, 256, 0, stream>>>(W_out, WoutT);
  reduce_prep_kernel<<<BATCH, 256, 0, stream>>>(ens, x_pred, innov, y_seq, W1, b1,
                                                a_buf, out_xs, out_Ps, -1);

  float* hc = h_a;  float* hn = h_b;
  ushort* hfc = hf_a; ushort* hfn = hf_b;
  for (int t = 0; t < SEQLEN; ++t) {
    uint32_t kt0, kt1, k1a, k1b, k2a, k2b;
    tf2x32(0u, 42u, 0u, (uint32_t)t, kt0, kt1);   // fold_in(key(42), t)
    tf2x32(kt0, kt1, 0u, 0u, k1a, k1b);           // dropout1 key
    tf2x32(kt0, kt1, 0u, 1u, k2a, k2b);           // dropout2 key

    a_ens_kernel<<<800, 256, 0, stream>>>(a_buf, AF, k1a, k1b);
    gru_mfma_kernel<<<200, 512, GRU_LDS_BYTES, stream>>>(AF, hfc, Wpk, hc,
                                                         b_ih, b_hh, hn, hfn);
    kvec_ens_kernel<<<MROWS, 256, 0, stream>>>(hn, WoutT, b_out, x_pred, innov, ens, k2a, k2b);
    reduce_prep_kernel<<<BATCH, 256, 0, stream>>>(ens, x_pred, innov, y_seq, W1, b1,
                                                  a_buf, out_xs, out_Ps, t);
    float* tmp = hc; hc = hn; hn = tmp;
    ushort* tmpf = hfc; hfc = hfn; hfn = tmpf;
  }
}